// Round 7
// baseline (135.615 us; speedup 1.0000x reference)
//
#include <hip/hip_runtime.h>
#include <stdint.h>

typedef __attribute__((ext_vector_type(4))) short short4v;
typedef __attribute__((ext_vector_type(8))) short bf16x8;
typedef __attribute__((ext_vector_type(4))) float f32x4;
typedef __attribute__((ext_vector_type(2))) uint32_t uint2v;
typedef __attribute__((ext_vector_type(4))) uint32_t uint4v;
typedef __attribute__((ext_vector_type(4))) uint16_t ushort4v;

#define NN 4096

__device__ __forceinline__ uint16_t f2bf(float f) {
    union { float f; uint32_t u; } c; c.f = f;
    uint32_t r = c.u + 0x7FFF + ((c.u >> 16) & 1);   // RNE
    return (uint16_t)(r >> 16);
}

// ---------------------------------------------------------------------------
// Kernel 1: weight transpose -> bf16 (tiny, runs first).
// ---------------------------------------------------------------------------
__global__ __launch_bounds__(256) void wpack_kernel(
    const float* __restrict__ Wq, const float* __restrict__ Wk,
    const float* __restrict__ Wv, const float* __restrict__ Wo,
    uint16_t* __restrict__ WT, uint16_t* __restrict__ WoT)
{
    const int t = blockIdx.x * 256 + threadIdx.x;   // 0..65535
    if (t < 3 * 128 * 128) {
        int j = t >> 7, k = t & 127;
        int m = j >> 7, jj = j & 127;
        const float* W = (m == 0) ? Wq : ((m == 1) ? Wk : Wv);
        float v = W[k * 128 + jj];
        if (m == 0) v *= (0.17677669529663687f * 1.4426950408889634f);
        WT[t] = f2bf(v);
    } else {
        int t2 = t - 3 * 128 * 128;
        int j = t2 >> 7, k = t2 & 127;
        WoT[t2] = f2bf(Wo[k * 128 + j]);
    }
}

// ---------------------------------------------------------------------------
// Kernel 2: FUSED adjacency-pack + QKV projection.
// blocks [0,768):   qkv, split 3 ways (m=0 Q, m=1 K, m=2 V)
// blocks [768,2816): adjacency -> bitmask
// ---------------------------------------------------------------------------
__global__ __launch_bounds__(256) void adjqkv_kernel(
    const int* __restrict__ adj, uint64_t* __restrict__ bits,
    const float* __restrict__ x, const uint16_t* __restrict__ WT,
    uint16_t* __restrict__ Q, uint16_t* __restrict__ Kf, uint16_t* __restrict__ Vf)
{
    const int blk = blockIdx.x;
    const int tid = threadIdx.x;
    const int wave = tid >> 6, lane = tid & 63;

    if (blk >= 768) {
        const int ablk = blk - 768;                    // 0..2047
        const int wid = (ablk * 256 + tid) >> 6;       // 0..8191
        const int TOT = (NN * NN) / 64;                // 262144
        for (int i = wid; i < TOT; i += 8192) {
            int v = adj[(size_t)i * 64 + lane];
            uint64_t m = __ballot(v != 0);
            if (lane == 0) bits[i] = m;
        }
        return;
    }

    const int g = lane >> 4, l15 = lane & 15;
    const int m = blk >> 8;                            // 0=Q 1=K 2=V
    const int ntile = (blk & 255) * 4 + wave;          // 0..1023
    const int n = ntile * 16 + l15;
    const int b = n >> 12, nn = n & 4095;

    const char* xrow = (const char*)x + (size_t)n * 512;
    bf16x8 xb[4];
#pragma unroll
    for (int ks = 0; ks < 4; ++ks) {
        f32x4 a = *(const f32x4*)(xrow + ks * 128 + g * 16);
        f32x4 c = *(const f32x4*)(xrow + ks * 128 + 64 + g * 16);
        bf16x8 f;
#pragma unroll
        for (int i = 0; i < 4; ++i) { f[i] = (short)f2bf(a[i]); f[4 + i] = (short)f2bf(c[i]); }
        xb[ks] = f;
    }

#pragma unroll 1
    for (int jt = m * 8; jt < m * 8 + 8; ++jt) {
        const int j0 = jt * 16;
        const bool isV = (m == 2);
        const char* wrow = (const char*)WT + (size_t)(j0 + l15) * 256;
        f32x4 acc = {0.f, 0.f, 0.f, 0.f};
#pragma unroll
        for (int ks = 0; ks < 4; ++ks) {
            short4v a0 = *(const short4v*)(wrow + ks * 64 + g * 8);
            short4v a1 = *(const short4v*)(wrow + ks * 64 + 32 + g * 8);
            bf16x8 af = __builtin_shufflevector(a0, a1, 0, 1, 2, 3, 4, 5, 6, 7);
            acc = isV ? __builtin_amdgcn_mfma_f32_16x16x32_bf16(xb[ks], af, acc, 0, 0, 0)
                      : __builtin_amdgcn_mfma_f32_16x16x32_bf16(af, xb[ks], acc, 0, 0, 0);
        }
        const int bh = b * 4 + ((j0 & 127) >> 5);
        const int half = (j0 >> 4) & 1;
        ushort4v st;
#pragma unroll
        for (int r = 0; r < 4; ++r) st[r] = f2bf(acc[r]);
        if (m == 0) {
            const int d0 = (j0 & 31) + g * 4;
            *(ushort4v*)(Q + ((size_t)bh * 4096 + nn) * 32 + d0) = st;
        } else if (m == 1) {
            *(ushort4v*)(Kf + ((size_t)bh << 17) + (ntile & 255) * 512 + lane * 8 + half * 4) = st;
        } else {
            *(ushort4v*)(Vf + ((size_t)bh << 17) + ((ntile & 255) >> 1) * 1024
                         + half * 512 + lane * 8 + ((ntile & 1) << 2)) = st;
        }
    }
}

// ---------------------------------------------------------------------------
// Kernel 3: flash attention. 256-thr blocks, 32 q-rows (qg=2), key-split 4.
// FULL 1-iteration-ahead register prefetch (K + V + masks) so loaded regs age
// a whole iteration (~500 issue cycles) before first use -> L2 latency
// (~200-400cy) fully covered. ~104 unified regs -> 4 waves/SIMD.
// ---------------------------------------------------------------------------
__global__ __launch_bounds__(256) void attn_kernel(
    const uint16_t* __restrict__ Q, const uint16_t* __restrict__ Kf,
    const uint16_t* __restrict__ Vf, const uint32_t* __restrict__ bits,
    uint16_t* __restrict__ O)
{
    __shared__ f32x4 cmb[4][2][2][64];   // [wave][qg][h][lane]
    __shared__ float csum[4][2][64];
    const int tid = threadIdx.x;
    const int wave = tid >> 6, lane = tid & 63;
    const int g = lane >> 4, l15 = lane & 15, gsh = g * 4;
    const int blk = blockIdx.x;
    const int bh = ((blk & 7) << 1) | ((blk >> 3) & 1);   // XCD-cluster bh
    const int qb = blk >> 4;                               // 0..127
    const int q0 = qb * 32;

    const char* Kp = (const char*)Kf + ((size_t)bh << 18) + wave * 65536 + lane * 16;
    const char* Vp = (const char*)Vf + ((size_t)bh << 18) + wave * 65536 + lane * 16;
    const uint32_t* ap0 = bits + (size_t)(q0 + l15) * 128 + wave * 32;
    const uint32_t* ap1 = bits + (size_t)(q0 + 16 + l15) * 128 + wave * 32;

    bf16x8 qf[2];
#pragma unroll
    for (int qg = 0; qg < 2; ++qg) {
        const char* qrow = (const char*)Q + ((size_t)bh * 4096 + q0 + qg * 16 + l15) * 64;
        short4v a0 = *(const short4v*)(qrow + g * 8);
        short4v a1 = *(const short4v*)(qrow + 32 + g * 8);
        qf[qg] = __builtin_shufflevector(a0, a1, 0, 1, 2, 3, 4, 5, 6, 7);
    }

    bf16x8 ones;
#pragma unroll
    for (int i = 0; i < 8; ++i) ones[i] = (short)0x3F80;   // bf16 1.0

    const f32x4 z = {0.f, 0.f, 0.f, 0.f};
    f32x4 o[2][2], sacc[2];
#pragma unroll
    for (int qg = 0; qg < 2; ++qg) { o[qg][0] = z; o[qg][1] = z; sacc[qg] = z; }

    auto compute = [&](const bf16x8 (&kc)[4], const bf16x8 (&vc)[4],
                       const uint2v w0, const uint2v w1) {
#pragma unroll
        for (int qg = 0; qg < 2; ++qg) {
            const uint2v wc = qg ? w1 : w0;
#pragma unroll
            for (int hf = 0; hf < 2; ++hf) {
                f32x4 s0 = __builtin_amdgcn_mfma_f32_16x16x32_bf16(kc[hf * 2], qf[qg], z, 0, 0, 0);
                f32x4 s1 = __builtin_amdgcn_mfma_f32_16x16x32_bf16(kc[hf * 2 + 1], qf[qg], z, 0, 0, 0);
                uint32_t wlo = wc[hf] >> gsh;
                uint32_t whi = wc[hf] >> (16 + gsh);
                float p[8];
#pragma unroll
                for (int r = 0; r < 4; ++r) {
                    float pv0 = __builtin_amdgcn_exp2f(s0[r]);
                    int m0 = ((int)(wlo << (31 - r))) >> 31;
                    p[r] = __uint_as_float(__float_as_uint(pv0) & (uint32_t)m0);
                    float pv1 = __builtin_amdgcn_exp2f(s1[r]);
                    int m1 = ((int)(whi << (31 - r))) >> 31;
                    p[4 + r] = __uint_as_float(__float_as_uint(pv1) & (uint32_t)m1);
                }
                uint32_t pk[4];
#pragma unroll
                for (int i = 0; i < 4; ++i) {
                    uint32_t r_;
                    asm("v_cvt_pk_bf16_f32 %0, %1, %2" : "=v"(r_) : "v"(p[2 * i]), "v"(p[2 * i + 1]));
                    pk[i] = r_;
                }
                uint4v u = {pk[0], pk[1], pk[2], pk[3]};
                bf16x8 pf = __builtin_bit_cast(bf16x8, u);
                o[qg][0] = __builtin_amdgcn_mfma_f32_16x16x32_bf16(vc[hf * 2], pf, o[qg][0], 0, 0, 0);
                o[qg][1] = __builtin_amdgcn_mfma_f32_16x16x32_bf16(vc[hf * 2 + 1], pf, o[qg][1], 0, 0, 0);
                sacc[qg] = __builtin_amdgcn_mfma_f32_16x16x32_bf16(ones, pf, sacc[qg], 0, 0, 0);
            }
        }
    };

    // prologue: load tile 0 into A registers
    bf16x8 kA[4], vA[4];
    uint2v wA0, wA1;
#pragma unroll
    for (int j = 0; j < 4; ++j) { kA[j] = *(const bf16x8*)(Kp + j * 1024); vA[j] = *(const bf16x8*)(Vp + j * 1024); }
    Kp += 4096; Vp += 4096;
    wA0 = *(const uint2v*)ap0; ap0 += 2;
    wA1 = *(const uint2v*)ap1; ap1 += 2;

#pragma unroll 1
    for (int t = 0; t < 16; t += 2) {
        // prefetch t+1 into B, compute A
        bf16x8 kB[4], vB[4];
        uint2v wB0, wB1;
#pragma unroll
        for (int j = 0; j < 4; ++j) { kB[j] = *(const bf16x8*)(Kp + j * 1024); vB[j] = *(const bf16x8*)(Vp + j * 1024); }
        Kp += 4096; Vp += 4096;
        wB0 = *(const uint2v*)ap0; ap0 += 2;
        wB1 = *(const uint2v*)ap1; ap1 += 2;
        compute(kA, vA, wA0, wA1);

        // prefetch t+2 into A (if any), compute B
        if (t + 2 < 16) {
#pragma unroll
            for (int j = 0; j < 4; ++j) { kA[j] = *(const bf16x8*)(Kp + j * 1024); vA[j] = *(const bf16x8*)(Vp + j * 1024); }
            Kp += 4096; Vp += 4096;
            wA0 = *(const uint2v*)ap0; ap0 += 2;
            wA1 = *(const uint2v*)ap1; ap1 += 2;
        }
        compute(kB, vB, wB0, wB1);
    }

    // combine across the 4 key-split waves
#pragma unroll
    for (int qg = 0; qg < 2; ++qg) {
        cmb[wave][qg][0][lane] = o[qg][0];
        cmb[wave][qg][1][lane] = o[qg][1];
        csum[wave][qg][lane] = sacc[qg][0];
    }
    __syncthreads();
    {
        const int qg = wave >> 1, h = wave & 1;
        f32x4 a = cmb[0][qg][h][lane] + cmb[1][qg][h][lane]
                + cmb[2][qg][h][lane] + cmb[3][qg][h][lane];
        float sd = csum[0][qg][lane] + csum[1][qg][lane]
                 + csum[2][qg][lane] + csum[3][qg][lane];
        const float inv = 1.0f / sd;
        const int q = q0 + qg * 16 + l15;
        uint16_t* orow = O + ((size_t)bh * 4096 + q) * 32;
        ushort4v st;
#pragma unroll
        for (int r = 0; r < 4; ++r) st[r] = f2bf(a[r] * inv);
        *(ushort4v*)(orow + h * 16 + gsh) = st;
    }
}

// ---------------------------------------------------------------------------
// Kernel 4: output projection, split 4 ways over output columns (grid 1024).
// ---------------------------------------------------------------------------
__global__ __launch_bounds__(256) void proj_kernel(
    const uint16_t* __restrict__ A, const uint16_t* __restrict__ WoT,
    const float* __restrict__ bo, float* __restrict__ out)
{
    const int wave = threadIdx.x >> 6, lane = threadIdx.x & 63;
    const int g = lane >> 4, l15 = lane & 15;
    const int blk = blockIdx.x;
    const int ctbase = (blk >> 8) * 2;                 // 0,2,4,6
    const int ntile = (blk & 255) * 4 + wave;
    const int n = ntile * 16 + l15;
    const int b = n >> 12, nn = n & 4095;

    bf16x8 bfr[4];
#pragma unroll
    for (int h = 0; h < 4; ++h) {
        const char* arow = (const char*)A + (((size_t)(b * 4 + h)) * 4096 + nn) * 64;
        short4v a0 = *(const short4v*)(arow + g * 8);
        short4v a1 = *(const short4v*)(arow + 32 + g * 8);
        bfr[h] = __builtin_shufflevector(a0, a1, 0, 1, 2, 3, 4, 5, 6, 7);
    }
#pragma unroll 1
    for (int ct = ctbase; ct < ctbase + 2; ++ct) {
        const int c0 = ct * 16;
        const char* wrow = (const char*)WoT + (size_t)(c0 + l15) * 256;
        f32x4 acc = {0.f, 0.f, 0.f, 0.f};
#pragma unroll
        for (int h = 0; h < 4; ++h) {
            short4v a0 = *(const short4v*)(wrow + h * 64 + g * 8);
            short4v a1 = *(const short4v*)(wrow + h * 64 + 32 + g * 8);
            bf16x8 af = __builtin_shufflevector(a0, a1, 0, 1, 2, 3, 4, 5, 6, 7);
            acc = __builtin_amdgcn_mfma_f32_16x16x32_bf16(af, bfr[h], acc, 0, 0, 0);
        }
        f32x4 bias = *(const f32x4*)(bo + c0 + g * 4);
#pragma unroll
        for (int r = 0; r < 4; ++r) acc[r] += bias[r];
        *(f32x4*)(out + (size_t)n * 128 + c0 + g * 4) = acc;
    }
}

// ---------------------------------------------------------------------------
extern "C" void kernel_launch(void* const* d_in, const int* in_sizes, int n_in,
                              void* d_out, int out_size, void* d_ws, size_t ws_size,
                              hipStream_t stream)
{
    const float* x   = (const float*)d_in[0];
    const int*   adj = (const int*)d_in[1];
    const float* Wq  = (const float*)d_in[2];
    const float* Wk  = (const float*)d_in[3];
    const float* Wv  = (const float*)d_in[4];
    const float* Wo  = (const float*)d_in[5];
    const float* bo  = (const float*)d_in[6];
    float* out = (float*)d_out;

    char* ws = (char*)d_ws;
    uint16_t* Q    = (uint16_t*)(ws);                       // 4 MB
    uint16_t* Kf   = (uint16_t*)(ws + ((size_t)4 << 20));   // 4 MB (fragment order)
    uint16_t* Vf   = (uint16_t*)(ws + ((size_t)8 << 20));   // 4 MB (fragment order)
    uint16_t* AO   = (uint16_t*)(ws + ((size_t)12 << 20));  // 4 MB
    uint32_t* bits = (uint32_t*)(ws + ((size_t)16 << 20));  // 2 MB
    uint16_t* WT   = (uint16_t*)(ws + ((size_t)18 << 20));  // 96 KB
    uint16_t* WoT  = (uint16_t*)(ws + ((size_t)18 << 20) + 98304); // 32 KB

    hipLaunchKernelGGL(wpack_kernel, dim3(256), dim3(256), 0, stream,
                       Wq, Wk, Wv, Wo, WT, WoT);
    hipLaunchKernelGGL(adjqkv_kernel, dim3(2816), dim3(256), 0, stream,
                       adj, (uint64_t*)bits, x, WT, Q, Kf, Vf);
    hipLaunchKernelGGL(attn_kernel, dim3(2048), dim3(256), 0, stream,
                       Q, Kf, Vf, bits, AO);
    hipLaunchKernelGGL(proj_kernel, dim3(1024), dim3(256), 0, stream,
                       AO, WoT, bo, out);
}

// Round 8
// 123.326 us; speedup vs baseline: 1.0996x; 1.0996x over previous
//
#include <hip/hip_runtime.h>
#include <stdint.h>

typedef __attribute__((ext_vector_type(4))) short short4v;
typedef __attribute__((ext_vector_type(8))) short bf16x8;
typedef __attribute__((ext_vector_type(4))) float f32x4;
typedef __attribute__((ext_vector_type(2))) uint32_t uint2v;
typedef __attribute__((ext_vector_type(4))) uint32_t uint4v;
typedef __attribute__((ext_vector_type(4))) uint16_t ushort4v;

#define NN 4096

__device__ __forceinline__ uint16_t f2bf(float f) {
    union { float f; uint32_t u; } c; c.f = f;
    uint32_t r = c.u + 0x7FFF + ((c.u >> 16) & 1);   // RNE
    return (uint16_t)(r >> 16);
}

// ---------------------------------------------------------------------------
// Kernel 1: weight transpose -> bf16 (tiny, runs first).
// Wq gets 1/sqrt(32)*log2(e) folded in (attn uses exp2 directly).
// ---------------------------------------------------------------------------
__global__ __launch_bounds__(256) void wpack_kernel(
    const float* __restrict__ Wq, const float* __restrict__ Wk,
    const float* __restrict__ Wv, const float* __restrict__ Wo,
    uint16_t* __restrict__ WT, uint16_t* __restrict__ WoT)
{
    const int t = blockIdx.x * 256 + threadIdx.x;   // 0..65535
    if (t < 3 * 128 * 128) {
        int j = t >> 7, k = t & 127;
        int m = j >> 7, jj = j & 127;
        const float* W = (m == 0) ? Wq : ((m == 1) ? Wk : Wv);
        float v = W[k * 128 + jj];
        if (m == 0) v *= (0.17677669529663687f * 1.4426950408889634f);
        WT[t] = f2bf(v);
    } else {
        int t2 = t - 3 * 128 * 128;
        int j = t2 >> 7, k = t2 & 127;
        WoT[t2] = f2bf(Wo[k * 128 + j]);
    }
}

// ---------------------------------------------------------------------------
// Kernel 2: FUSED adjacency-pack + QKV projection.
// blocks [0,768):   qkv, split 3 ways (m=0 Q, m=1 K, m=2 V)
// blocks [768,2816): adjacency -> bitmask. Contiguous 32-word chunks per
// wave, 4-way batched loads (amortize L2/HBM latency 4x vs 1-load-per-iter).
// ---------------------------------------------------------------------------
__global__ __launch_bounds__(256) void adjqkv_kernel(
    const int* __restrict__ adj, uint64_t* __restrict__ bits,
    const float* __restrict__ x, const uint16_t* __restrict__ WT,
    uint16_t* __restrict__ Q, uint16_t* __restrict__ Kf, uint16_t* __restrict__ Vf)
{
    const int blk = blockIdx.x;
    const int tid = threadIdx.x;
    const int wave = tid >> 6, lane = tid & 63;

    if (blk >= 768) {
        // ---- adjacency pack: wave wid owns words [wid*32, wid*32+32) ----
        const int ablk = blk - 768;                    // 0..2047
        const int wid = (ablk * 256 + tid) >> 6;       // 0..8191
        const int base = wid * 32;
        const int* src = adj + (size_t)base * 64 + lane;
#pragma unroll 1
        for (int ii = 0; ii < 32; ii += 4) {
            int v0 = src[(ii + 0) * 64];
            int v1 = src[(ii + 1) * 64];
            int v2 = src[(ii + 2) * 64];
            int v3 = src[(ii + 3) * 64];
            uint64_t m0 = __ballot(v0 != 0);
            uint64_t m1 = __ballot(v1 != 0);
            uint64_t m2 = __ballot(v2 != 0);
            uint64_t m3 = __ballot(v3 != 0);
            if (lane == 0) {
                bits[base + ii + 0] = m0;
                bits[base + ii + 1] = m1;
                bits[base + ii + 2] = m2;
                bits[base + ii + 3] = m3;
            }
        }
        return;
    }

    // ---- qkv ----
    const int g = lane >> 4, l15 = lane & 15;
    const int m = blk >> 8;                            // 0=Q 1=K 2=V
    const int ntile = (blk & 255) * 4 + wave;          // 0..1023
    const int n = ntile * 16 + l15;
    const int b = n >> 12, nn = n & 4095;

    const char* xrow = (const char*)x + (size_t)n * 512;
    bf16x8 xb[4];
#pragma unroll
    for (int ks = 0; ks < 4; ++ks) {
        f32x4 a = *(const f32x4*)(xrow + ks * 128 + g * 16);
        f32x4 c = *(const f32x4*)(xrow + ks * 128 + 64 + g * 16);
        bf16x8 f;
#pragma unroll
        for (int i = 0; i < 4; ++i) { f[i] = (short)f2bf(a[i]); f[4 + i] = (short)f2bf(c[i]); }
        xb[ks] = f;
    }

#pragma unroll 1
    for (int jt = m * 8; jt < m * 8 + 8; ++jt) {
        const int j0 = jt * 16;
        const bool isV = (m == 2);
        const char* wrow = (const char*)WT + (size_t)(j0 + l15) * 256;
        f32x4 acc = {0.f, 0.f, 0.f, 0.f};
#pragma unroll
        for (int ks = 0; ks < 4; ++ks) {
            short4v a0 = *(const short4v*)(wrow + ks * 64 + g * 8);
            short4v a1 = *(const short4v*)(wrow + ks * 64 + 32 + g * 8);
            bf16x8 af = __builtin_shufflevector(a0, a1, 0, 1, 2, 3, 4, 5, 6, 7);
            acc = isV ? __builtin_amdgcn_mfma_f32_16x16x32_bf16(xb[ks], af, acc, 0, 0, 0)
                      : __builtin_amdgcn_mfma_f32_16x16x32_bf16(af, xb[ks], acc, 0, 0, 0);
        }
        const int bh = b * 4 + ((j0 & 127) >> 5);
        const int half = (j0 >> 4) & 1;
        ushort4v st;
#pragma unroll
        for (int r = 0; r < 4; ++r) st[r] = f2bf(acc[r]);
        if (m == 0) {
            const int d0 = (j0 & 31) + g * 4;
            *(ushort4v*)(Q + ((size_t)bh * 4096 + nn) * 32 + d0) = st;
        } else if (m == 1) {
            *(ushort4v*)(Kf + ((size_t)bh << 17) + (ntile & 255) * 512 + lane * 8 + half * 4) = st;
        } else {
            *(ushort4v*)(Vf + ((size_t)bh << 17) + ((ntile & 255) >> 1) * 1024
                         + half * 512 + lane * 8 + ((ntile & 1) << 2)) = st;
        }
    }
}

// ---------------------------------------------------------------------------
// Kernel 3: flash attention — round-3 structure (best measured: 78 us) +
// T5 s_setprio around MFMA clusters (measured +4-7% on attn, m191 regime:
// independent waves, no main-loop barrier).
// Block = 4 waves, 64 q-rows (qg=4); waves split keys 4-way (1024 each).
// K + mask register double-buffer; V loaded in-body. LDS combine at end.
// ---------------------------------------------------------------------------
__global__ __launch_bounds__(256) void attn_kernel(
    const uint16_t* __restrict__ Q, const uint16_t* __restrict__ Kf,
    const uint16_t* __restrict__ Vf, const uint32_t* __restrict__ bits,
    uint16_t* __restrict__ O)
{
    __shared__ f32x4 cmb[4][4][2][64];   // [wave][qg][h][lane]
    __shared__ float csum[4][4][64];
    const int tid = threadIdx.x;
    const int wave = tid >> 6, lane = tid & 63;
    const int g = lane >> 4, l15 = lane & 15, gsh = g * 4;
    const int blk = blockIdx.x;
    const int bh = ((blk & 7) << 1) | ((blk >> 3) & 1);   // XCD-cluster bh
    const int qb = blk >> 4;
    const int q0 = qb * 64;

    const char* Kp = (const char*)Kf + ((size_t)bh << 18) + wave * 65536 + lane * 16;
    const char* Vp = (const char*)Vf + ((size_t)bh << 18) + wave * 65536 + lane * 16;
    const uint32_t* ap[4];
#pragma unroll
    for (int qg = 0; qg < 4; ++qg)
        ap[qg] = bits + (size_t)(q0 + qg * 16 + l15) * 128 + wave * 32;

    bf16x8 qf[4];
#pragma unroll
    for (int qg = 0; qg < 4; ++qg) {
        const char* qrow = (const char*)Q + ((size_t)bh * 4096 + q0 + qg * 16 + l15) * 64;
        short4v a0 = *(const short4v*)(qrow + g * 8);
        short4v a1 = *(const short4v*)(qrow + 32 + g * 8);
        qf[qg] = __builtin_shufflevector(a0, a1, 0, 1, 2, 3, 4, 5, 6, 7);
    }

    bf16x8 ones;
#pragma unroll
    for (int i = 0; i < 8; ++i) ones[i] = (short)0x3F80;   // bf16 1.0

    const f32x4 z = {0.f, 0.f, 0.f, 0.f};
    f32x4 o[4][2], sacc[4];
#pragma unroll
    for (int qg = 0; qg < 4; ++qg) { o[qg][0] = z; o[qg][1] = z; sacc[qg] = z; }

    bf16x8 kc[4], kn[4];
    uint2v wc[4], wn[4];
#pragma unroll
    for (int j = 0; j < 4; ++j) kc[j] = *(const bf16x8*)(Kp + j * 1024);
    Kp += 4096;
#pragma unroll
    for (int qg = 0; qg < 4; ++qg) { wc[qg] = *(const uint2v*)ap[qg]; ap[qg] += 2; }

    auto body = [&](bf16x8 (&kcur)[4], uint2v (&wcur)[4],
                    bf16x8 (&knxt)[4], uint2v (&wnxt)[4]) {
        // prefetch next K tile + masks
#pragma unroll
        for (int j = 0; j < 4; ++j) knxt[j] = *(const bf16x8*)(Kp + j * 1024);
        Kp += 4096;
#pragma unroll
        for (int qg = 0; qg < 4; ++qg) { wnxt[qg] = *(const uint2v*)ap[qg]; ap[qg] += 2; }
        // current V tile (latency hidden under QK/softmax)
        bf16x8 vc[4];
#pragma unroll
        for (int i = 0; i < 4; ++i) vc[i] = *(const bf16x8*)(Vp + i * 1024);
        Vp += 4096;

#pragma unroll
        for (int qg = 0; qg < 4; ++qg) {
            f32x4 s[4];
            __builtin_amdgcn_s_setprio(1);
#pragma unroll
            for (int j = 0; j < 4; ++j)
                s[j] = __builtin_amdgcn_mfma_f32_16x16x32_bf16(kcur[j], qf[qg], z, 0, 0, 0);
            __builtin_amdgcn_s_setprio(0);
            float p[16];
#pragma unroll
            for (int j = 0; j < 4; ++j) {
                uint32_t wj = wcur[qg][j >> 1] >> (((j & 1) << 4) + gsh);
#pragma unroll
                for (int r = 0; r < 4; ++r) {
                    float pv = __builtin_amdgcn_exp2f(s[j][r]);
                    int msk = ((int)(wj << (31 - r))) >> 31;
                    p[j * 4 + r] = __uint_as_float(__float_as_uint(pv) & (uint32_t)msk);
                }
            }
            uint32_t pk[8];
#pragma unroll
            for (int i = 0; i < 8; ++i) {
                uint32_t r_;
                asm("v_cvt_pk_bf16_f32 %0, %1, %2" : "=v"(r_) : "v"(p[2 * i]), "v"(p[2 * i + 1]));
                pk[i] = r_;
            }
            uint4v u0 = {pk[0], pk[1], pk[2], pk[3]};
            uint4v u1 = {pk[4], pk[5], pk[6], pk[7]};
            bf16x8 pf0 = __builtin_bit_cast(bf16x8, u0);
            bf16x8 pf1 = __builtin_bit_cast(bf16x8, u1);
            __builtin_amdgcn_s_setprio(1);
            o[qg][0] = __builtin_amdgcn_mfma_f32_16x16x32_bf16(vc[0], pf0, o[qg][0], 0, 0, 0);
            o[qg][0] = __builtin_amdgcn_mfma_f32_16x16x32_bf16(vc[2], pf1, o[qg][0], 0, 0, 0);
            o[qg][1] = __builtin_amdgcn_mfma_f32_16x16x32_bf16(vc[1], pf0, o[qg][1], 0, 0, 0);
            o[qg][1] = __builtin_amdgcn_mfma_f32_16x16x32_bf16(vc[3], pf1, o[qg][1], 0, 0, 0);
            sacc[qg] = __builtin_amdgcn_mfma_f32_16x16x32_bf16(ones, pf0, sacc[qg], 0, 0, 0);
            sacc[qg] = __builtin_amdgcn_mfma_f32_16x16x32_bf16(ones, pf1, sacc[qg], 0, 0, 0);
            __builtin_amdgcn_s_setprio(0);
        }
    };

#pragma unroll 1
    for (int tt = 0; tt < 16; tt += 2) {
        body(kc, wc, kn, wn);
        body(kn, wn, kc, wc);
    }

    // write partials, combine across the 4 key-split waves
#pragma unroll
    for (int qg = 0; qg < 4; ++qg) {
        cmb[wave][qg][0][lane] = o[qg][0];
        cmb[wave][qg][1][lane] = o[qg][1];
        csum[wave][qg][lane] = sacc[qg][0];
    }
    __syncthreads();
    {
        const int qg = wave;   // wave w finalizes q-group w
        f32x4 a0 = cmb[0][qg][0][lane];
        f32x4 a1 = cmb[0][qg][1][lane];
        float sd = csum[0][qg][lane];
#pragma unroll
        for (int v = 1; v < 4; ++v) {
            a0 += cmb[v][qg][0][lane];
            a1 += cmb[v][qg][1][lane];
            sd += csum[v][qg][lane];
        }
        const float inv = 1.0f / sd;
        const int q = q0 + qg * 16 + l15;
        uint16_t* orow = O + ((size_t)bh * 4096 + q) * 32;
        ushort4v st0, st1;
#pragma unroll
        for (int r = 0; r < 4; ++r) {
            st0[r] = f2bf(a0[r] * inv);
            st1[r] = f2bf(a1[r] * inv);
        }
        *(ushort4v*)(orow + gsh) = st0;
        *(ushort4v*)(orow + 16 + gsh) = st1;
    }
}

// ---------------------------------------------------------------------------
// Kernel 4: output projection, split 4 ways over output columns (grid 1024).
// ---------------------------------------------------------------------------
__global__ __launch_bounds__(256) void proj_kernel(
    const uint16_t* __restrict__ A, const uint16_t* __restrict__ WoT,
    const float* __restrict__ bo, float* __restrict__ out)
{
    const int wave = threadIdx.x >> 6, lane = threadIdx.x & 63;
    const int g = lane >> 4, l15 = lane & 15;
    const int blk = blockIdx.x;
    const int ctbase = (blk >> 8) * 2;                 // 0,2,4,6
    const int ntile = (blk & 255) * 4 + wave;
    const int n = ntile * 16 + l15;
    const int b = n >> 12, nn = n & 4095;

    bf16x8 bfr[4];
#pragma unroll
    for (int h = 0; h < 4; ++h) {
        const char* arow = (const char*)A + (((size_t)(b * 4 + h)) * 4096 + nn) * 64;
        short4v a0 = *(const short4v*)(arow + g * 8);
        short4v a1 = *(const short4v*)(arow + 32 + g * 8);
        bfr[h] = __builtin_shufflevector(a0, a1, 0, 1, 2, 3, 4, 5, 6, 7);
    }
#pragma unroll 1
    for (int ct = ctbase; ct < ctbase + 2; ++ct) {
        const int c0 = ct * 16;
        const char* wrow = (const char*)WoT + (size_t)(c0 + l15) * 256;
        f32x4 acc = {0.f, 0.f, 0.f, 0.f};
#pragma unroll
        for (int h = 0; h < 4; ++h) {
            short4v a0 = *(const short4v*)(wrow + h * 64 + g * 8);
            short4v a1 = *(const short4v*)(wrow + h * 64 + 32 + g * 8);
            bf16x8 af = __builtin_shufflevector(a0, a1, 0, 1, 2, 3, 4, 5, 6, 7);
            acc = __builtin_amdgcn_mfma_f32_16x16x32_bf16(af, bfr[h], acc, 0, 0, 0);
        }
        f32x4 bias = *(const f32x4*)(bo + c0 + g * 4);
#pragma unroll
        for (int r = 0; r < 4; ++r) acc[r] += bias[r];
        *(f32x4*)(out + (size_t)n * 128 + c0 + g * 4) = acc;
    }
}

// ---------------------------------------------------------------------------
extern "C" void kernel_launch(void* const* d_in, const int* in_sizes, int n_in,
                              void* d_out, int out_size, void* d_ws, size_t ws_size,
                              hipStream_t stream)
{
    const float* x   = (const float*)d_in[0];
    const int*   adj = (const int*)d_in[1];
    const float* Wq  = (const float*)d_in[2];
    const float* Wk  = (const float*)d_in[3];
    const float* Wv  = (const float*)d_in[4];
    const float* Wo  = (const float*)d_in[5];
    const float* bo  = (const float*)d_in[6];
    float* out = (float*)d_out;

    char* ws = (char*)d_ws;
    uint16_t* Q    = (uint16_t*)(ws);                       // 4 MB
    uint16_t* Kf   = (uint16_t*)(ws + ((size_t)4 << 20));   // 4 MB (fragment order)
    uint16_t* Vf   = (uint16_t*)(ws + ((size_t)8 << 20));   // 4 MB (fragment order)
    uint16_t* AO   = (uint16_t*)(ws + ((size_t)12 << 20));  // 4 MB
    uint32_t* bits = (uint32_t*)(ws + ((size_t)16 << 20));  // 2 MB
    uint16_t* WT   = (uint16_t*)(ws + ((size_t)18 << 20));  // 96 KB
    uint16_t* WoT  = (uint16_t*)(ws + ((size_t)18 << 20) + 98304); // 32 KB

    hipLaunchKernelGGL(wpack_kernel, dim3(256), dim3(256), 0, stream,
                       Wq, Wk, Wv, Wo, WT, WoT);
    hipLaunchKernelGGL(adjqkv_kernel, dim3(2816), dim3(256), 0, stream,
                       adj, (uint64_t*)bits, x, WT, Q, Kf, Vf);
    hipLaunchKernelGGL(attn_kernel, dim3(1024), dim3(256), 0, stream,
                       Q, Kf, Vf, bits, AO);
    hipLaunchKernelGGL(proj_kernel, dim3(1024), dim3(256), 0, stream,
                       AO, WoT, bo, out);
}

// Round 10
// 120.730 us; speedup vs baseline: 1.1233x; 1.0215x over previous
//
#include <hip/hip_runtime.h>
#include <stdint.h>

typedef __attribute__((ext_vector_type(4))) short short4v;
typedef __attribute__((ext_vector_type(8))) short bf16x8;
typedef __attribute__((ext_vector_type(4))) float f32x4;
typedef __attribute__((ext_vector_type(2))) uint32_t uint2v;
typedef __attribute__((ext_vector_type(4))) uint32_t uint4v;
typedef __attribute__((ext_vector_type(4))) uint16_t ushort4v;

#define NN 4096

__device__ __forceinline__ uint16_t f2bf(float f) {
    union { float f; uint32_t u; } c; c.f = f;
    uint32_t r = c.u + 0x7FFF + ((c.u >> 16) & 1);   // RNE
    return (uint16_t)(r >> 16);
}

// ---------------------------------------------------------------------------
// Kernel 1: weight transpose -> bf16 (tiny, runs first).
// Wq gets 1/sqrt(32)*log2(e) folded in (attn uses exp2 directly).
// ---------------------------------------------------------------------------
__global__ __launch_bounds__(256) void wpack_kernel(
    const float* __restrict__ Wq, const float* __restrict__ Wk,
    const float* __restrict__ Wv, const float* __restrict__ Wo,
    uint16_t* __restrict__ WT, uint16_t* __restrict__ WoT)
{
    const int t = blockIdx.x * 256 + threadIdx.x;   // 0..65535
    if (t < 3 * 128 * 128) {
        int j = t >> 7, k = t & 127;
        int m = j >> 7, jj = j & 127;
        const float* W = (m == 0) ? Wq : ((m == 1) ? Wk : Wv);
        float v = W[k * 128 + jj];
        if (m == 0) v *= (0.17677669529663687f * 1.4426950408889634f);
        WT[t] = f2bf(v);
    } else {
        int t2 = t - 3 * 128 * 128;
        int j = t2 >> 7, k = t2 & 127;
        WoT[t2] = f2bf(Wo[k * 128 + j]);
    }
}

// ---------------------------------------------------------------------------
// Kernel 2: FUSED adjacency-pack + QKV projection.
// blocks [0,768):   qkv, split 3 ways (m=0 Q, m=1 K, m=2 V)
// blocks [768,2816): adjacency -> bitmask, stored TRANSPOSED as u32 slabs:
//   bitsT32[w32 * 4096 + row], w32 = 32-key group (0..127), row = query row.
// Attn's hot-loop mask read then hits consecutive rows at fixed w32 ->
// perfectly coalesced 4B/lane. Scatter cost moves here (one-time stores).
// ---------------------------------------------------------------------------
__global__ __launch_bounds__(256) void adjqkv_kernel(
    const int* __restrict__ adj, uint32_t* __restrict__ bitsT32,
    const float* __restrict__ x, const uint16_t* __restrict__ WT,
    uint16_t* __restrict__ Q, uint16_t* __restrict__ Kf, uint16_t* __restrict__ Vf)
{
    const int blk = blockIdx.x;
    const int tid = threadIdx.x;
    const int wave = tid >> 6, lane = tid & 63;

    if (blk >= 768) {
        // ---- adjacency pack: wave wid owns row-major u64 words
        //      [wid*32, wid*32+32) — all within one row ----
        const int ablk = blk - 768;                    // 0..2047
        const int wid = (ablk * 256 + tid) >> 6;       // 0..8191
        const int base = wid * 32;                     // u64-word index
        const int row = base >> 6;
        const int w64b = base & 63;                    // 0 or 32
        const int* src = adj + (size_t)base * 64 + lane;
#pragma unroll 1
        for (int ii = 0; ii < 32; ii += 4) {
            int v0 = src[(ii + 0) * 64];
            int v1 = src[(ii + 1) * 64];
            int v2 = src[(ii + 2) * 64];
            int v3 = src[(ii + 3) * 64];
            uint64_t m0 = __ballot(v0 != 0);
            uint64_t m1 = __ballot(v1 != 0);
            uint64_t m2 = __ballot(v2 != 0);
            uint64_t m3 = __ballot(v3 != 0);
            if (lane == 0) {
                const int w0 = (w64b + ii) * 2;        // u32 slab index
                bitsT32[(size_t)(w0 + 0) * 4096 + row] = (uint32_t)m0;
                bitsT32[(size_t)(w0 + 1) * 4096 + row] = (uint32_t)(m0 >> 32);
                bitsT32[(size_t)(w0 + 2) * 4096 + row] = (uint32_t)m1;
                bitsT32[(size_t)(w0 + 3) * 4096 + row] = (uint32_t)(m1 >> 32);
                bitsT32[(size_t)(w0 + 4) * 4096 + row] = (uint32_t)m2;
                bitsT32[(size_t)(w0 + 5) * 4096 + row] = (uint32_t)(m2 >> 32);
                bitsT32[(size_t)(w0 + 6) * 4096 + row] = (uint32_t)m3;
                bitsT32[(size_t)(w0 + 7) * 4096 + row] = (uint32_t)(m3 >> 32);
            }
        }
        return;
    }

    // ---- qkv ----
    const int g = lane >> 4, l15 = lane & 15;
    const int m = blk >> 8;                            // 0=Q 1=K 2=V
    const int ntile = (blk & 255) * 4 + wave;          // 0..1023
    const int n = ntile * 16 + l15;
    const int b = n >> 12, nn = n & 4095;

    const char* xrow = (const char*)x + (size_t)n * 512;
    bf16x8 xb[4];
#pragma unroll
    for (int ks = 0; ks < 4; ++ks) {
        f32x4 a = *(const f32x4*)(xrow + ks * 128 + g * 16);
        f32x4 c = *(const f32x4*)(xrow + ks * 128 + 64 + g * 16);
        bf16x8 f;
#pragma unroll
        for (int i = 0; i < 4; ++i) { f[i] = (short)f2bf(a[i]); f[4 + i] = (short)f2bf(c[i]); }
        xb[ks] = f;
    }

#pragma unroll 1
    for (int jt = m * 8; jt < m * 8 + 8; ++jt) {
        const int j0 = jt * 16;
        const bool isV = (m == 2);
        const char* wrow = (const char*)WT + (size_t)(j0 + l15) * 256;
        f32x4 acc = {0.f, 0.f, 0.f, 0.f};
#pragma unroll
        for (int ks = 0; ks < 4; ++ks) {
            short4v a0 = *(const short4v*)(wrow + ks * 64 + g * 8);
            short4v a1 = *(const short4v*)(wrow + ks * 64 + 32 + g * 8);
            bf16x8 af = __builtin_shufflevector(a0, a1, 0, 1, 2, 3, 4, 5, 6, 7);
            acc = isV ? __builtin_amdgcn_mfma_f32_16x16x32_bf16(xb[ks], af, acc, 0, 0, 0)
                      : __builtin_amdgcn_mfma_f32_16x16x32_bf16(af, xb[ks], acc, 0, 0, 0);
        }
        const int bh = b * 4 + ((j0 & 127) >> 5);
        const int half = (j0 >> 4) & 1;
        ushort4v st;
#pragma unroll
        for (int r = 0; r < 4; ++r) st[r] = f2bf(acc[r]);
        if (m == 0) {
            const int d0 = (j0 & 31) + g * 4;
            *(ushort4v*)(Q + ((size_t)bh * 4096 + nn) * 32 + d0) = st;
        } else if (m == 1) {
            *(ushort4v*)(Kf + ((size_t)bh << 17) + (ntile & 255) * 512 + lane * 8 + half * 4) = st;
        } else {
            *(ushort4v*)(Vf + ((size_t)bh << 17) + ((ntile & 255) >> 1) * 1024
                         + half * 512 + lane * 8 + ((ntile & 1) << 2)) = st;
        }
    }
}

// ---------------------------------------------------------------------------
// Kernel 3: flash attention — R8-proven structure; ONLY change: mask loads
// come from the transposed u32 slabs (coalesced: consecutive rows at fixed
// w32) instead of the row-major 16-line gather. Extraction code identical to
// R8. All prefetches guarded (no OOB). Direct indexing, no pointer mutation.
// Block = 4 waves, 64 q-rows (qg=4); waves split keys 4-way (1024 each).
// ---------------------------------------------------------------------------
__global__ __launch_bounds__(256) void attn_kernel(
    const uint16_t* __restrict__ Q, const uint16_t* __restrict__ Kf,
    const uint16_t* __restrict__ Vf, const uint32_t* __restrict__ bitsT32,
    uint16_t* __restrict__ O)
{
    __shared__ f32x4 cmb[4][4][2][64];   // [wave][qg][h][lane]
    __shared__ float csum[4][4][64];
    const int tid = threadIdx.x;
    const int wave = tid >> 6, lane = tid & 63;
    const int g = lane >> 4, l15 = lane & 15, gsh = g * 4;
    const int blk = blockIdx.x;
    const int bh = ((blk & 7) << 1) | ((blk >> 3) & 1);   // XCD-cluster bh
    const int qb = blk >> 4;
    const int q0 = qb * 64;

    const char* Kbase = (const char*)Kf + ((size_t)bh << 18) + wave * 65536 + lane * 16;
    const char* Vbase = (const char*)Vf + ((size_t)bh << 18) + wave * 65536 + lane * 16;
    // transposed masks: tile t -> mb[qg][(2t)*4096] (lo) and [(2t+1)*4096] (hi)
    const uint32_t* mb[4];
#pragma unroll
    for (int qg = 0; qg < 4; ++qg)
        mb[qg] = bitsT32 + (size_t)(wave * 32) * 4096 + (q0 + qg * 16 + l15);

    bf16x8 qf[4];
#pragma unroll
    for (int qg = 0; qg < 4; ++qg) {
        const char* qrow = (const char*)Q + ((size_t)bh * 4096 + q0 + qg * 16 + l15) * 64;
        short4v a0 = *(const short4v*)(qrow + g * 8);
        short4v a1 = *(const short4v*)(qrow + 32 + g * 8);
        qf[qg] = __builtin_shufflevector(a0, a1, 0, 1, 2, 3, 4, 5, 6, 7);
    }

    bf16x8 ones;
#pragma unroll
    for (int i = 0; i < 8; ++i) ones[i] = (short)0x3F80;   // bf16 1.0

    const f32x4 z = {0.f, 0.f, 0.f, 0.f};
    f32x4 o[4][2], sacc[4];
#pragma unroll
    for (int qg = 0; qg < 4; ++qg) { o[qg][0] = z; o[qg][1] = z; sacc[qg] = z; }

    bf16x8 kc[4], kn[4];
    uint2v wc[4], wn[4];
    // prologue: tile 0
#pragma unroll
    for (int j = 0; j < 4; ++j) kc[j] = *(const bf16x8*)(Kbase + j * 1024);
#pragma unroll
    for (int qg = 0; qg < 4; ++qg) {
        wc[qg][0] = mb[qg][0];
        wc[qg][1] = mb[qg][4096];
    }

    auto body = [&](int tcur, int tnxt, bf16x8 (&kcur)[4], uint2v (&wcur)[4],
                    bf16x8 (&knxt)[4], uint2v (&wnxt)[4]) {
        // guarded prefetch of next K tile + masks
        if (tnxt < 16) {
#pragma unroll
            for (int j = 0; j < 4; ++j)
                knxt[j] = *(const bf16x8*)(Kbase + (size_t)tnxt * 4096 + j * 1024);
#pragma unroll
            for (int qg = 0; qg < 4; ++qg) {
                wnxt[qg][0] = mb[qg][(size_t)(2 * tnxt) * 4096];
                wnxt[qg][1] = mb[qg][(size_t)(2 * tnxt + 1) * 4096];
            }
        }
        // current V tile (latency hidden under QK/softmax)
        bf16x8 vc[4];
#pragma unroll
        for (int i = 0; i < 4; ++i)
            vc[i] = *(const bf16x8*)(Vbase + (size_t)tcur * 4096 + i * 1024);

#pragma unroll
        for (int qg = 0; qg < 4; ++qg) {
            f32x4 s[4];
#pragma unroll
            for (int j = 0; j < 4; ++j)
                s[j] = __builtin_amdgcn_mfma_f32_16x16x32_bf16(kcur[j], qf[qg], z, 0, 0, 0);
            float p[16];
#pragma unroll
            for (int j = 0; j < 4; ++j) {
                uint32_t wj = wcur[qg][j >> 1] >> (((j & 1) << 4) + gsh);
#pragma unroll
                for (int r = 0; r < 4; ++r) {
                    float pv = __builtin_amdgcn_exp2f(s[j][r]);
                    int msk = ((int)(wj << (31 - r))) >> 31;
                    p[j * 4 + r] = __uint_as_float(__float_as_uint(pv) & (uint32_t)msk);
                }
            }
            uint32_t pk[8];
#pragma unroll
            for (int i = 0; i < 8; ++i) {
                uint32_t r_;
                asm("v_cvt_pk_bf16_f32 %0, %1, %2" : "=v"(r_) : "v"(p[2 * i]), "v"(p[2 * i + 1]));
                pk[i] = r_;
            }
            uint4v u0 = {pk[0], pk[1], pk[2], pk[3]};
            uint4v u1 = {pk[4], pk[5], pk[6], pk[7]};
            bf16x8 pf0 = __builtin_bit_cast(bf16x8, u0);
            bf16x8 pf1 = __builtin_bit_cast(bf16x8, u1);
            o[qg][0] = __builtin_amdgcn_mfma_f32_16x16x32_bf16(vc[0], pf0, o[qg][0], 0, 0, 0);
            o[qg][0] = __builtin_amdgcn_mfma_f32_16x16x32_bf16(vc[2], pf1, o[qg][0], 0, 0, 0);
            o[qg][1] = __builtin_amdgcn_mfma_f32_16x16x32_bf16(vc[1], pf0, o[qg][1], 0, 0, 0);
            o[qg][1] = __builtin_amdgcn_mfma_f32_16x16x32_bf16(vc[3], pf1, o[qg][1], 0, 0, 0);
            sacc[qg] = __builtin_amdgcn_mfma_f32_16x16x32_bf16(ones, pf0, sacc[qg], 0, 0, 0);
            sacc[qg] = __builtin_amdgcn_mfma_f32_16x16x32_bf16(ones, pf1, sacc[qg], 0, 0, 0);
        }
    };

#pragma unroll 1
    for (int tt = 0; tt < 16; tt += 2) {
        body(tt, tt + 1, kc, wc, kn, wn);
        body(tt + 1, tt + 2, kn, wn, kc, wc);
    }

    // write partials, combine across the 4 key-split waves
#pragma unroll
    for (int qg = 0; qg < 4; ++qg) {
        cmb[wave][qg][0][lane] = o[qg][0];
        cmb[wave][qg][1][lane] = o[qg][1];
        csum[wave][qg][lane] = sacc[qg][0];
    }
    __syncthreads();
    {
        const int qg = wave;   // wave w finalizes q-group w
        f32x4 a0 = cmb[0][qg][0][lane];
        f32x4 a1 = cmb[0][qg][1][lane];
        float sd = csum[0][qg][lane];
#pragma unroll
        for (int v = 1; v < 4; ++v) {
            a0 += cmb[v][qg][0][lane];
            a1 += cmb[v][qg][1][lane];
            sd += csum[v][qg][lane];
        }
        const float inv = 1.0f / sd;
        const int q = q0 + qg * 16 + l15;
        uint16_t* orow = O + ((size_t)bh * 4096 + q) * 32;
        ushort4v st0, st1;
#pragma unroll
        for (int r = 0; r < 4; ++r) {
            st0[r] = f2bf(a0[r] * inv);
            st1[r] = f2bf(a1[r] * inv);
        }
        *(ushort4v*)(orow + gsh) = st0;
        *(ushort4v*)(orow + 16 + gsh) = st1;
    }
}

// ---------------------------------------------------------------------------
// Kernel 4: output projection, split 4 ways over output columns (grid 1024).
// ---------------------------------------------------------------------------
__global__ __launch_bounds__(256) void proj_kernel(
    const uint16_t* __restrict__ A, const uint16_t* __restrict__ WoT,
    const float* __restrict__ bo, float* __restrict__ out)
{
    const int wave = threadIdx.x >> 6, lane = threadIdx.x & 63;
    const int g = lane >> 4, l15 = lane & 15;
    const int blk = blockIdx.x;
    const int ctbase = (blk >> 8) * 2;                 // 0,2,4,6
    const int ntile = (blk & 255) * 4 + wave;
    const int n = ntile * 16 + l15;
    const int b = n >> 12, nn = n & 4095;

    bf16x8 bfr[4];
#pragma unroll
    for (int h = 0; h < 4; ++h) {
        const char* arow = (const char*)A + (((size_t)(b * 4 + h)) * 4096 + nn) * 64;
        short4v a0 = *(const short4v*)(arow + g * 8);
        short4v a1 = *(const short4v*)(arow + 32 + g * 8);
        bfr[h] = __builtin_shufflevector(a0, a1, 0, 1, 2, 3, 4, 5, 6, 7);
    }
#pragma unroll 1
    for (int ct = ctbase; ct < ctbase + 2; ++ct) {
        const int c0 = ct * 16;
        const char* wrow = (const char*)WoT + (size_t)(c0 + l15) * 256;
        f32x4 acc = {0.f, 0.f, 0.f, 0.f};
#pragma unroll
        for (int h = 0; h < 4; ++h) {
            short4v a0 = *(const short4v*)(wrow + h * 64 + g * 8);
            short4v a1 = *(const short4v*)(wrow + h * 64 + 32 + g * 8);
            bf16x8 af = __builtin_shufflevector(a0, a1, 0, 1, 2, 3, 4, 5, 6, 7);
            acc = __builtin_amdgcn_mfma_f32_16x16x32_bf16(af, bfr[h], acc, 0, 0, 0);
        }
        f32x4 bias = *(const f32x4*)(bo + c0 + g * 4);
#pragma unroll
        for (int r = 0; r < 4; ++r) acc[r] += bias[r];
        *(f32x4*)(out + (size_t)n * 128 + c0 + g * 4) = acc;
    }
}

// ---------------------------------------------------------------------------
extern "C" void kernel_launch(void* const* d_in, const int* in_sizes, int n_in,
                              void* d_out, int out_size, void* d_ws, size_t ws_size,
                              hipStream_t stream)
{
    const float* x   = (const float*)d_in[0];
    const int*   adj = (const int*)d_in[1];
    const float* Wq  = (const float*)d_in[2];
    const float* Wk  = (const float*)d_in[3];
    const float* Wv  = (const float*)d_in[4];
    const float* Wo  = (const float*)d_in[5];
    const float* bo  = (const float*)d_in[6];
    float* out = (float*)d_out;

    char* ws = (char*)d_ws;
    uint16_t* Q      = (uint16_t*)(ws);                       // 4 MB
    uint16_t* Kf     = (uint16_t*)(ws + ((size_t)4 << 20));   // 4 MB (fragment order)
    uint16_t* Vf     = (uint16_t*)(ws + ((size_t)8 << 20));   // 4 MB (fragment order)
    uint16_t* AO     = (uint16_t*)(ws + ((size_t)12 << 20));  // 4 MB
    uint32_t* bitsT32= (uint32_t*)(ws + ((size_t)16 << 20));  // 2 MB (transposed u32 slabs)
    uint16_t* WT     = (uint16_t*)(ws + ((size_t)18 << 20));  // 96 KB
    uint16_t* WoT    = (uint16_t*)(ws + ((size_t)18 << 20) + 98304); // 32 KB

    hipLaunchKernelGGL(wpack_kernel, dim3(256), dim3(256), 0, stream,
                       Wq, Wk, Wv, Wo, WT, WoT);
    hipLaunchKernelGGL(adjqkv_kernel, dim3(2816), dim3(256), 0, stream,
                       adj, bitsT32, x, WT, Q, Kf, Vf);
    hipLaunchKernelGGL(attn_kernel, dim3(1024), dim3(256), 0, stream,
                       Q, Kf, Vf, bitsT32, AO);
    hipLaunchKernelGGL(proj_kernel, dim3(1024), dim3(256), 0, stream,
                       AO, WoT, bo, out);
}